// Round 1
// baseline (1010.184 us; speedup 1.0000x reference)
//
#include <hip/hip_runtime.h>

#define NEG (-1e30f)

// One wave (64 lanes) per row of V=1024 logits. Computes logsumexp and
// writes blank = lp[...,0] and emit = lp[...,label] (masked past y_len).
__global__ __launch_bounds__(256) void rnnt_softmax_gather(
    const float* __restrict__ logits, const int* __restrict__ labels,
    const int* __restrict__ y_len,
    float* __restrict__ blank_ws, float* __restrict__ emit_ws,
    int B, int T, int U, int rows)
{
    const int V = 1024;
    int widx = threadIdx.x >> 6;
    int lane = threadIdx.x & 63;
    int r = blockIdx.x * 4 + widx;
    if (r >= rows) return;

    int U1 = U + 1;
    int u  = r % U1;
    int bt = r / U1;
    int b  = bt / T;
    int t  = bt % T;

    const float*  rowp  = logits + (size_t)r * V;
    const float4* rowp4 = reinterpret_cast<const float4*>(rowp);

    float4 v0 = rowp4[lane];
    float4 v1 = rowp4[lane + 64];
    float4 v2 = rowp4[lane + 128];
    float4 v3 = rowp4[lane + 192];

    // Early scalar fetch of the label logit (lane 0 only) to overlap latency.
    bool has_emit = (u < U);
    float lab_logit = 0.f;
    if (has_emit && lane == 0) {
        int label = labels[b * U + u];
        lab_logit = rowp[label];
    }

    float m = fmaxf(fmaxf(fmaxf(v0.x, v0.y), fmaxf(v0.z, v0.w)),
                    fmaxf(fmaxf(v1.x, v1.y), fmaxf(v1.z, v1.w)));
    m = fmaxf(m, fmaxf(fmaxf(v2.x, v2.y), fmaxf(v2.z, v2.w)));
    m = fmaxf(m, fmaxf(fmaxf(v3.x, v3.y), fmaxf(v3.z, v3.w)));
    #pragma unroll
    for (int off = 32; off; off >>= 1) m = fmaxf(m, __shfl_xor(m, off));

    float s = __expf(v0.x - m) + __expf(v0.y - m) + __expf(v0.z - m) + __expf(v0.w - m)
            + __expf(v1.x - m) + __expf(v1.y - m) + __expf(v1.z - m) + __expf(v1.w - m)
            + __expf(v2.x - m) + __expf(v2.y - m) + __expf(v2.z - m) + __expf(v2.w - m)
            + __expf(v3.x - m) + __expf(v3.y - m) + __expf(v3.z - m) + __expf(v3.w - m);
    #pragma unroll
    for (int off = 32; off; off >>= 1) s += __shfl_xor(s, off);

    if (lane == 0) {
        float lse = m + __logf(s);
        blank_ws[r] = v0.x - lse;           // lane 0's v0.x == rowp[0]
        if (has_emit) {
            float e = lab_logit - lse;
            if (u >= y_len[b]) e = NEG;
            emit_ws[(b * T + t) * U + u] = e;
        }
    }
}

// Anti-diagonal wavefront over the (t,u) alpha grid. One block per batch.
// alpha[t,u] = logaddexp(alpha[t-1,u] + blank[t-1,u],
//                        alpha[t,u-1] + emit[t,u-1])
__global__ __launch_bounds__(128) void rnnt_alpha(
    const float* __restrict__ blank_ws, const float* __restrict__ emit_ws,
    const int* __restrict__ f_len, const int* __restrict__ y_len,
    float* __restrict__ out, int B, int T, int U)
{
    int b = blockIdx.x;
    int u = threadIdx.x;
    int U1 = U + 1;

    __shared__ float buf[2 * 256];   // supports U1 <= 256
    float* b0 = buf;
    float* b1 = buf + U1;

    int t_last = f_len[b] - 1;
    int yl     = y_len[b];
    const float* blank_b = blank_ws + (size_t)b * T * U1;
    const float* emit_b  = emit_ws  + (size_t)b * T * U;

    int D = T + U;  // diagonals d = t + u, d in [0, T-1+U]
    for (int d = 0; d < D; ++d) {
        float* cur        = (d & 1) ? b1 : b0;
        const float* prev = (d & 1) ? b0 : b1;
        int lo = max(0, d - (T - 1));
        int hi = min(U, d);
        if (u >= lo && u <= hi) {
            int t = d - u;
            float a;
            if (d == 0) {
                a = 0.f;
            } else if (t == 0) {
                a = prev[u - 1] + emit_b[u - 1];
            } else if (u == 0) {
                a = prev[0] + blank_b[(size_t)(t - 1) * U1];
            } else {
                float x = prev[u]     + blank_b[(size_t)(t - 1) * U1 + u];
                float y = prev[u - 1] + emit_b[(size_t)t * U + (u - 1)];
                float mm = fmaxf(x, y);
                a = mm + log1pf(__expf(fminf(x, y) - mm));
            }
            cur[u] = a;
            if (t == t_last && u == yl) {
                float ll = a + blank_b[(size_t)t * U1 + u];
                atomicAdd(out, -ll / (float)B);
            }
        }
        __syncthreads();
    }
}

extern "C" void kernel_launch(void* const* d_in, const int* in_sizes, int n_in,
                              void* d_out, int out_size, void* d_ws, size_t ws_size,
                              hipStream_t stream) {
    const float* logits = (const float*)d_in[0];
    const int*   labels = (const int*)d_in[1];
    const int*   f_len  = (const int*)d_in[2];
    const int*   y_len  = (const int*)d_in[3];

    const int V  = 1024;
    int B  = in_sizes[2];
    int U  = in_sizes[1] / B;
    int U1 = U + 1;
    int T  = (int)((long long)in_sizes[0] / ((long long)B * U1 * V));
    int rows = B * T * U1;

    float* blank_ws = (float*)d_ws;
    float* emit_ws  = blank_ws + rows;

    hipMemsetAsync(d_out, 0, sizeof(float), stream);

    dim3 grid1((rows + 3) / 4);
    rnnt_softmax_gather<<<grid1, 256, 0, stream>>>(
        logits, labels, y_len, blank_ws, emit_ws, B, T, U, rows);

    rnnt_alpha<<<B, 128, 0, stream>>>(
        blank_ws, emit_ws, f_len, y_len, (float*)d_out, B, T, U);
}

// Round 2
// 753.571 us; speedup vs baseline: 1.3405x; 1.3405x over previous
//
#include <hip/hip_runtime.h>

#define NEG (-1e30f)

// One wave (64 lanes) per row of V=1024 logits. Computes logsumexp and
// writes blank = lp[...,0] and emit = lp[...,label] (masked past y_len),
// TRANSPOSED to [b][u][t] so the alpha kernel streams contiguously.
__global__ __launch_bounds__(256) void rnnt_softmax_gather(
    const float* __restrict__ logits, const int* __restrict__ labels,
    const int* __restrict__ f_len, const int* __restrict__ y_len,
    float* __restrict__ blankT, float* __restrict__ emitT,
    int B, int T, int U, int rows)
{
    const int V = 1024;
    int widx = threadIdx.x >> 6;
    int lane = threadIdx.x & 63;
    int r = blockIdx.x * 4 + widx;
    if (r >= rows) return;

    int U1 = U + 1;
    int u  = r % U1;
    int bt = r / U1;
    int b  = bt / T;
    int t  = bt % T;

    // alpha never reads t >= f_len[b]; skip the whole row (saves ~25% HBM).
    if (t >= f_len[b]) return;

    const float*  rowp  = logits + (size_t)r * V;
    const float4* rowp4 = reinterpret_cast<const float4*>(rowp);

    float4 v0 = rowp4[lane];
    float4 v1 = rowp4[lane + 64];
    float4 v2 = rowp4[lane + 128];
    float4 v3 = rowp4[lane + 192];

    bool has_emit = (u < U);
    float lab_logit = 0.f;
    if (has_emit && lane == 0) {
        int label = labels[b * U + u];
        lab_logit = rowp[label];
    }

    float m = fmaxf(fmaxf(fmaxf(v0.x, v0.y), fmaxf(v0.z, v0.w)),
                    fmaxf(fmaxf(v1.x, v1.y), fmaxf(v1.z, v1.w)));
    m = fmaxf(m, fmaxf(fmaxf(v2.x, v2.y), fmaxf(v2.z, v2.w)));
    m = fmaxf(m, fmaxf(fmaxf(v3.x, v3.y), fmaxf(v3.z, v3.w)));
    #pragma unroll
    for (int off = 32; off; off >>= 1) m = fmaxf(m, __shfl_xor(m, off));

    float s = __expf(v0.x - m) + __expf(v0.y - m) + __expf(v0.z - m) + __expf(v0.w - m)
            + __expf(v1.x - m) + __expf(v1.y - m) + __expf(v1.z - m) + __expf(v1.w - m)
            + __expf(v2.x - m) + __expf(v2.y - m) + __expf(v2.z - m) + __expf(v2.w - m)
            + __expf(v3.x - m) + __expf(v3.y - m) + __expf(v3.z - m) + __expf(v3.w - m);
    #pragma unroll
    for (int off = 32; off; off >>= 1) s += __shfl_xor(s, off);

    if (lane == 0) {
        float lse = m + __logf(s);
        blankT[((size_t)b * U1 + u) * T + t] = v0.x - lse;  // lane0 v0.x == rowp[0]
        if (has_emit) {
            float e = lab_logit - lse;
            if (u >= y_len[b]) e = NEG;
            emitT[((size_t)b * U + u) * T + t] = e;
        }
    }
}

// Anti-diagonal wavefront, one block per batch. Thread u owns grid column u
// and streams blankT/emitT rows contiguously (t increments per diagonal).
// alpha[t,u] = logaddexp(alpha[t-1,u] + blank[t-1,u],
//                        alpha[t,u-1] + emit[t,u-1])
// Neighbor term (alpha + emit at cell (t,u-1)) is passed via LDS: thread u-1
// computed exactly that value on the previous diagonal.
__global__ __launch_bounds__(128) void rnnt_alpha(
    const float* __restrict__ blankT, const float* __restrict__ emitT,
    const int* __restrict__ f_len, const int* __restrict__ y_len,
    float* __restrict__ out, int B, int T, int U)
{
    int b = blockIdx.x;
    int u = threadIdx.x;
    int U1 = U + 1;

    __shared__ float sbuf[2][80];

    int t_last = f_len[b] - 1;
    int yl     = y_len[b];
    const float* blank_row = blankT + ((size_t)b * U1 + u) * T;
    const float* emit_row  = emitT  + ((size_t)b * U  + u) * T;

    float a      = NEG;
    float bl_cur = NEG;                               // blank[t-1] for own row
    float em_cur = (u < U) ? emit_row[0] : 0.f;       // emit[t] for own row

    int D = t_last + yl;     // last diagonal that matters (termination cell)
    for (int d = 0; d <= D; ++d) {
        int t = d - u;
        if (u < U1 && t >= 0 && t < T) {
            float x = (t > 0) ? a + bl_cur : NEG;
            float y = (u > 0) ? sbuf[(d ^ 1) & 1][u - 1] : NEG;
            float mx = fmaxf(x, y);
            float mn = fminf(x, y);
            float na = mx + __logf(1.f + __expf(mn - mx));
            a = (d == 0) ? 0.f : na;
            if (u < U) sbuf[d & 1][u] = a + em_cur;
            if (t == t_last && u == yl) {
                float ll = a + blank_row[t_last];
                atomicAdd(out, -ll * (1.0f / (float)B));
            }
            // prefetch next diagonal's operands (own t advances by 1)
            bl_cur = blank_row[t];
            if (u < U && t + 1 < T) em_cur = emit_row[t + 1];
        }
        __syncthreads();
    }
}

extern "C" void kernel_launch(void* const* d_in, const int* in_sizes, int n_in,
                              void* d_out, int out_size, void* d_ws, size_t ws_size,
                              hipStream_t stream) {
    const float* logits = (const float*)d_in[0];
    const int*   labels = (const int*)d_in[1];
    const int*   f_len  = (const int*)d_in[2];
    const int*   y_len  = (const int*)d_in[3];

    const int V  = 1024;
    int B  = in_sizes[2];
    int U  = in_sizes[1] / B;
    int U1 = U + 1;
    int T  = (int)((long long)in_sizes[0] / ((long long)B * U1 * V));
    int rows = B * T * U1;

    float* blankT = (float*)d_ws;                 // [B][U1][T]
    float* emitT  = blankT + (size_t)B * U1 * T;  // [B][U][T]

    hipMemsetAsync(d_out, 0, sizeof(float), stream);

    dim3 grid1((rows + 3) / 4);
    rnnt_softmax_gather<<<grid1, 256, 0, stream>>>(
        logits, labels, f_len, y_len, blankT, emitT, B, T, U, rows);

    rnnt_alpha<<<B, 128, 0, stream>>>(
        blankT, emitT, f_len, y_len, (float*)d_out, B, T, U);
}

// Round 3
// 724.407 us; speedup vs baseline: 1.3945x; 1.0403x over previous
//
#include <hip/hip_runtime.h>

#define NEG (-1e30f)

// One wave (64 lanes) per row of V=1024 logits. Computes logsumexp, writes
// blank = lp[...,0] and emit = lp[...,label] in ANTI-DIAGONAL layout:
//   blankD[b][t+u][u]  (u <= y_len),  emitD[b][t+u][u]  (u < y_len)
// so the alpha kernel's per-diagonal reads are coalesced across lanes.
// Rows with t >= f_len[b] or u > y_len[b] are skipped entirely (never read).
__global__ __launch_bounds__(256) void rnnt_softmax_gather(
    const float* __restrict__ logits, const int* __restrict__ labels,
    const int* __restrict__ f_len, const int* __restrict__ y_len,
    float* __restrict__ blankD, float* __restrict__ emitD,
    int B, int T, int U, int rows)
{
    const int V = 1024;
    int widx = threadIdx.x >> 6;
    int lane = threadIdx.x & 63;
    int r = blockIdx.x * 4 + widx;
    if (r >= rows) return;

    int U1 = U + 1;
    int u  = r % U1;
    int bt = r / U1;
    int b  = bt / T;
    int t  = bt % T;

    // Dead rows: never read by the alpha recurrence.
    if (t >= f_len[b] || u > y_len[b]) return;

    const float*  rowp  = logits + (size_t)r * V;
    const float4* rowp4 = reinterpret_cast<const float4*>(rowp);

    bool has_emit = (u < U) && (u < y_len[b]);
    float lab_logit = 0.f;
    if (has_emit && lane == 0) {
        int label = labels[b * U + u];
        lab_logit = rowp[label];
    }

    float4 v0 = rowp4[lane];
    float4 v1 = rowp4[lane + 64];
    float4 v2 = rowp4[lane + 128];
    float4 v3 = rowp4[lane + 192];

    float m = fmaxf(fmaxf(fmaxf(v0.x, v0.y), fmaxf(v0.z, v0.w)),
                    fmaxf(fmaxf(v1.x, v1.y), fmaxf(v1.z, v1.w)));
    m = fmaxf(m, fmaxf(fmaxf(v2.x, v2.y), fmaxf(v2.z, v2.w)));
    m = fmaxf(m, fmaxf(fmaxf(v3.x, v3.y), fmaxf(v3.z, v3.w)));
    #pragma unroll
    for (int off = 32; off; off >>= 1) m = fmaxf(m, __shfl_xor(m, off));

    float s = __expf(v0.x - m) + __expf(v0.y - m) + __expf(v0.z - m) + __expf(v0.w - m)
            + __expf(v1.x - m) + __expf(v1.y - m) + __expf(v1.z - m) + __expf(v1.w - m)
            + __expf(v2.x - m) + __expf(v2.y - m) + __expf(v2.z - m) + __expf(v2.w - m)
            + __expf(v3.x - m) + __expf(v3.y - m) + __expf(v3.z - m) + __expf(v3.w - m);
    #pragma unroll
    for (int off = 32; off; off >>= 1) s += __shfl_xor(s, off);

    if (lane == 0) {
        float lse = m + __logf(s);
        int d = t + u;
        blankD[((size_t)b * (T + U) + d) * U1 + u] = v0.x - lse; // lane0 v0.x == rowp[0]
        if (has_emit) {
            emitD[((size_t)b * (T + U) + d) * U + u] = lab_logit - lse;
        }
    }
}

// Anti-diagonal wavefront, ONE WAVE per batch, no LDS, no barriers.
// Lane u owns grid column u; column 64 (only if y_len==64) folded onto lane 63.
// Left-neighbor term alpha(t,u-1)+emit(t,u-1) arrives via __shfl_up of the
// z value each lane computed on the previous diagonal. Per-diagonal operand
// reads are coalesced (diagonal layout) and hidden by a depth-8 register
// prefetch ring.
__global__ __launch_bounds__(64) void rnnt_alpha(
    const float* __restrict__ blankD, const float* __restrict__ emitD,
    const int* __restrict__ f_len, const int* __restrict__ y_len,
    float* __restrict__ out, int B, int T, int U)
{
    int b = blockIdx.x;
    int u = threadIdx.x;          // 0..63
    int U1 = U + 1;

    int t_last = f_len[b] - 1;
    int yl     = y_len[b];
    const float* bDb = blankD + (size_t)b * (T + U) * U1;
    const float* eDb = emitD  + (size_t)b * (T + U) * U;
    int D = t_last + yl;          // final diagonal holding the terminal cell
    bool has64 = (yl == U) && (U == 64);
    float invB = 1.0f / (float)B;

    constexpr int PD = 8;
    float pb[PD], pe[PD], pb64[PD];
    #pragma unroll
    for (int k = 0; k < PD; ++k) {
        int d  = (k <= D) ? k : D;
        int ib = (d >= 1) ? d - 1 : 0;
        pb[k]   = bDb[(size_t)ib * U1 + u];     // blank(t-1,u) for diag d
        pe[k]   = eDb[(size_t)d  * U  + u];     // emit(t,u)   for diag d
        pb64[k] = bDb[(size_t)ib * U1 + 64];    // blank(t64-1,64) (lane63 use)
    }

    float a = NEG, z = NEG, a64 = NEG;

    for (int dd = 0; dd <= D; dd += PD) {
        #pragma unroll
        for (int k = 0; k < PD; ++k) {
            int d = dd + k;
            if (d <= D) {
                float z_old  = z;                 // lane63: its z from diag d-1
                float z_left = __shfl_up(z, 1);   // neighbor's z from diag d-1
                int  t   = d - u;
                bool act = (t >= 0) && (t <= t_last) && (u <= yl);

                float x = (act && t > 0) ? a + pb[k] : NEG;
                float y = (act && u > 0) ? z_left   : NEG;
                float mx = fmaxf(x, y), mn = fminf(x, y);
                float na = mx + __logf(1.0f + __expf(mn - mx));
                if (d == 0 && u == 0) na = 0.0f;
                if (act) a = na;
                z = act ? (a + ((u < yl) ? pe[k] : NEG)) : NEG;

                if (act && t == t_last && u == yl) {
                    float bl = bDb[(size_t)(t_last + yl) * U1 + yl]; // blank(t_last,yl)
                    atomicAdd(out, -(a + bl) * invB);
                }

                if (has64) {                      // column 64, lane 63
                    int  t64    = d - 64;
                    bool a64act = (u == 63) && (t64 >= 0) && (t64 <= t_last);
                    float x4 = (a64act && t64 > 0) ? a64 + pb64[k] : NEG;
                    float y4 = a64act ? z_old : NEG;  // alpha(t64,63)+emit(t64,63)
                    float mx4 = fmaxf(x4, y4), mn4 = fminf(x4, y4);
                    float na4 = mx4 + __logf(1.0f + __expf(mn4 - mx4));
                    if (a64act) a64 = na4;
                    if (a64act && t64 == t_last) {
                        float bl4 = bDb[(size_t)(t_last + 64) * U1 + 64];
                        atomicAdd(out, -(a64 + bl4) * invB);
                    }
                }

                // refill slot k for diagonal d+PD (clamped; dup loads harmless)
                int dn  = d + PD; if (dn > D) dn = D;
                int ibn = (dn >= 1) ? dn - 1 : 0;
                pb[k]   = bDb[(size_t)ibn * U1 + u];
                pe[k]   = eDb[(size_t)dn  * U  + u];
                pb64[k] = bDb[(size_t)ibn * U1 + 64];
            }
        }
    }
}

extern "C" void kernel_launch(void* const* d_in, const int* in_sizes, int n_in,
                              void* d_out, int out_size, void* d_ws, size_t ws_size,
                              hipStream_t stream) {
    const float* logits = (const float*)d_in[0];
    const int*   labels = (const int*)d_in[1];
    const int*   f_len  = (const int*)d_in[2];
    const int*   y_len  = (const int*)d_in[3];

    const int V  = 1024;
    int B  = in_sizes[2];
    int U  = in_sizes[1] / B;
    int U1 = U + 1;
    int T  = (int)((long long)in_sizes[0] / ((long long)B * U1 * V));
    int rows = B * T * U1;

    float* blankD = (float*)d_ws;                       // [B][T+U][U1]
    float* emitD  = blankD + (size_t)B * (T + U) * U1;  // [B][T+U][U]

    hipMemsetAsync(d_out, 0, sizeof(float), stream);

    dim3 grid1((rows + 3) / 4);
    rnnt_softmax_gather<<<grid1, 256, 0, stream>>>(
        logits, labels, f_len, y_len, blankD, emitD, B, T, U, rows);

    rnnt_alpha<<<B, 64, 0, stream>>>(
        blankD, emitD, f_len, y_len, (float*)d_out, B, T, U);
}